// Round 1
// baseline (462.980 us; speedup 1.0000x reference)
//
#include <hip/hip_runtime.h>

// CrossScan: x (B=16, C=96, H=128, W=128) fp32 ->
// out (B, 4, C, H*W):
//   s=0: y0[b,c,h*W+w]          = x[b,c,h,w]
//   s=1: y1[b,c,w*H+h]          = x[b,c,h,w]   (HW transpose)
//   s=2: y2[b,c,i]              = y0[b,c,HW-1-i]
//   s=3: y3[b,c,i]              = y1[b,c,HW-1-i]
//
// Memory-bound: 96 MiB read + 384 MiB write. LDS 64x64 tile transpose for
// y1/y3; all four output streams written as coalesced float4.

#define Hh 128
#define Ww 128
#define HWp (Hh * Ww)
#define Cc 96
#define Bb 16
#define TILE 64

__global__ __launch_bounds__(1024) void cross_scan_kernel(
    const float* __restrict__ x, float* __restrict__ out) {
  // +1 pad: LDS bank = (4*tx + k + ty) % 32 -> 2-way aliasing only (free)
  __shared__ float tile[TILE][TILE + 1];

  const int tx = threadIdx.x;  // 0..15, handles 4 consecutive floats
  const int ty = threadIdx.y;  // 0..63, one row of the tile
  const int tileId = blockIdx.x;            // 0..3 (2x2 tiles of 64 in 128x128)
  const int tileRow = (tileId >> 1) * TILE; // base h
  const int tileCol = (tileId & 1) * TILE;  // base w
  const int plane = blockIdx.y;             // 0..B*C-1
  const int b = plane / Cc;
  const int c = plane - b * Cc;

  const float* xp = x + (size_t)plane * HWp;
  float* out0 = out + ((size_t)(b * 4 + 0) * Cc + c) * HWp;
  float* out1 = out + ((size_t)(b * 4 + 1) * Cc + c) * HWp;
  float* out2 = out + ((size_t)(b * 4 + 2) * Cc + c) * HWp;
  float* out3 = out + ((size_t)(b * 4 + 3) * Cc + c) * HWp;

  const int row = tileRow + ty;       // h
  const int col = tileCol + tx * 4;   // w (4-wide)
  const int idx = row * Ww + col;

  const float4 v = *(const float4*)(xp + idx);

  // y0: identity (coalesced)
  *(float4*)(out0 + idx) = v;
  // y2: reversed last axis; element idx+k -> HW-1-idx-k, so reversed float4
  // lands at HW-4-idx (16B aligned since idx % 4 == 0).
  *(float4*)(out2 + (HWp - 4 - idx)) = make_float4(v.w, v.z, v.y, v.x);

  // Stage tile for transpose: tile[r][cc] = x[tileRow+r][tileCol+cc]
  tile[ty][tx * 4 + 0] = v.x;
  tile[ty][tx * 4 + 1] = v.y;
  tile[ty][tx * 4 + 2] = v.z;
  tile[ty][tx * 4 + 3] = v.w;
  __syncthreads();

  // y1: o = w*H + h with w = tileCol+ty (fixed per thread), h = tileRow+4tx+k.
  // Consecutive lanes (tx) write consecutive addresses -> coalesced.
  float4 t;
  t.x = tile[tx * 4 + 0][ty];
  t.y = tile[tx * 4 + 1][ty];
  t.z = tile[tx * 4 + 2][ty];
  t.w = tile[tx * 4 + 3][ty];
  const int o = (tileCol + ty) * Hh + tileRow + tx * 4;
  *(float4*)(out1 + o) = t;
  // y3: reversed y1
  *(float4*)(out3 + (HWp - 4 - o)) = make_float4(t.w, t.z, t.y, t.x);
}

extern "C" void kernel_launch(void* const* d_in, const int* in_sizes, int n_in,
                              void* d_out, int out_size, void* d_ws,
                              size_t ws_size, hipStream_t stream) {
  const float* x = (const float*)d_in[0];
  float* out = (float*)d_out;
  dim3 grid(4, Bb * Cc);   // 4 tiles per plane, 1536 planes
  dim3 block(16, 64);      // 1024 threads, 16 waves
  cross_scan_kernel<<<grid, block, 0, stream>>>(x, out);
}

// Round 2
// 461.845 us; speedup vs baseline: 1.0025x; 1.0025x over previous
//
#include <hip/hip_runtime.h>

// CrossScan: x (B=16, C=96, H=128, W=128) fp32 -> out (B, 4, C, H*W):
//   s=0: y0[h*W+w] = x[h,w]
//   s=1: y1[w*H+h] = x[h,w]        (HW transpose)
//   s=2: y2[i]     = y0[HW-1-i]    (reverse)
//   s=3: y3[i]     = y1[HW-1-i]
//
// Memory-bound: 96 MiB read + 384 MiB write -> ~76 us floor at 6.3 TB/s.
// All four output streams stored with strictly ASCENDING coalesced float4:
// reversal is done via flipped LDS reads (the reversed image of an aligned
// 64x64 tile is another aligned 64x64 tile with both axes flipped).
// 256-thread blocks (4 waves) for 8 blocks/CU and 4 loads in flight/thread.

#define Hh 128
#define Ww 128
#define HWp (Hh * Ww)
#define Cc 96
#define Bb 16
#define TILE 64

__global__ __launch_bounds__(256) void cross_scan_kernel(
    const float* __restrict__ x, float* __restrict__ out) {
  // pad +1: row stride 65 = 1 mod 32 -> all access patterns are 2-way (free)
  __shared__ float tile[TILE][TILE + 1];

  const int tx = threadIdx.x;               // 0..15: float4 across 64 cols
  const int ty = threadIdx.y;               // 0..15: row base, rows ty+16j
  const int tileId = blockIdx.x;            // 0..3
  const int r0 = (tileId >> 1) * TILE;      // tile row base (h)
  const int c0 = (tileId & 1) * TILE;       // tile col base (w)
  const int plane = blockIdx.y;             // 0..B*C-1
  const int b = plane / Cc;
  const int c = plane - b * Cc;

  const float* xp = x + (size_t)plane * HWp;
  float* out0 = out + ((size_t)(b * 4 + 0) * Cc + c) * HWp;
  float* out1 = out + ((size_t)(b * 4 + 1) * Cc + c) * HWp;
  float* out2 = out + ((size_t)(b * 4 + 2) * Cc + c) * HWp;
  float* out3 = out + ((size_t)(b * 4 + 3) * Cc + c) * HWp;

  // ---- Phase 1: load 4 float4s, write y0 (ascending), stage tile ----
  float4 v[4];
#pragma unroll
  for (int j = 0; j < 4; ++j) {
    const int r = ty + 16 * j;
    v[j] = *(const float4*)(xp + (r0 + r) * Ww + c0 + tx * 4);
  }
#pragma unroll
  for (int j = 0; j < 4; ++j) {
    const int r = ty + 16 * j;
    *(float4*)(out0 + (r0 + r) * Ww + c0 + tx * 4) = v[j];
    tile[r][tx * 4 + 0] = v[j].x;
    tile[r][tx * 4 + 1] = v[j].y;
    tile[r][tx * 4 + 2] = v[j].z;
    tile[r][tx * 4 + 3] = v[j].w;
  }
  __syncthreads();

  // Flipped tile bases in the output image (H=W=128, tiles are 64-aligned):
  const int r2b = TILE - r0;  // y2 out-row base (row flip)
  const int c2b = TILE - c0;  // y2 out-col base (col flip)
  const int R3b = TILE - c0;  // y3 out-row base
  const int c3b = TILE - r0;  // y3 out-col base

  // ---- Phase 2: y1/y2/y3 via LDS, all stores ascending float4 ----
#pragma unroll
  for (int j = 0; j < 4; ++j) {
    const int R = ty + 16 * j;

    // y1[(c0+R)*W + r0+4tx+k] = x[r0+4tx+k][c0+R] = tile[4tx+k][R]
    float4 t1;
    t1.x = tile[tx * 4 + 0][R];
    t1.y = tile[tx * 4 + 1][R];
    t1.z = tile[tx * 4 + 2][R];
    t1.w = tile[tx * 4 + 3][R];
    *(float4*)(out1 + (c0 + R) * Hh + r0 + tx * 4) = t1;

    // y2[(r2b+R)*W + c2b+4tx+k] = y0[HW-1-that] = tile[63-R][63-4tx-k]
    const float* Trow = &tile[63 - R][0];
    float4 t2;
    t2.x = Trow[63 - tx * 4];
    t2.y = Trow[62 - tx * 4];
    t2.z = Trow[61 - tx * 4];
    t2.w = Trow[60 - tx * 4];
    *(float4*)(out2 + (r2b + R) * Ww + c2b + tx * 4) = t2;

    // y3[(R3b+R)*W + c3b+4tx+k] = y1[HW-1-that] = tile[63-4tx-k][63-R]
    float4 t3;
    t3.x = tile[63 - tx * 4][63 - R];
    t3.y = tile[62 - tx * 4][63 - R];
    t3.z = tile[61 - tx * 4][63 - R];
    t3.w = tile[60 - tx * 4][63 - R];
    *(float4*)(out3 + (R3b + R) * Hh + c3b + tx * 4) = t3;
  }
}

extern "C" void kernel_launch(void* const* d_in, const int* in_sizes, int n_in,
                              void* d_out, int out_size, void* d_ws,
                              size_t ws_size, hipStream_t stream) {
  const float* x = (const float*)d_in[0];
  float* out = (float*)d_out;
  dim3 grid(4, Bb * Cc);  // 4 tiles/plane, 1536 planes
  dim3 block(16, 16);     // 256 threads, 4 waves
  cross_scan_kernel<<<grid, block, 0, stream>>>(x, out);
}